// Round 9
// baseline (30.937 us; speedup 1.0000x reference)
//
#include <hip/hip_runtime.h>
#include <math.h>

// RandISH, per-b mapping + VGPR staging + plain cached stores (no LDS):
//   out[b, 2n+0] = Al(deg_n, r_b) * y0_norm[n] * P_l(ct)
//   out[b, 2n+1] = Al * cscale[n] * (-1)^deg * Re[(rx + i*ry)^deg]
// rv = vec[b] @ M[n]; rotation preserves |vec|=1 -> no normalization.
//
// One thread per direction b. The base loop is fully unrolled, so every
// per-n quantity (deg, mats, coeffs, scales) is wave-uniform with LITERAL
// offsets -> scalar loads into SGPRs, uniform branches, and the Re[z^d]
// recurrence runs only deg-1 real iterations (~54% of degs are 1). R4
// measured this compute model at VALUBusy 4.6% -- ~0.2 inst/output.
//
// Store fix (R4 died at WRITE_SIZE=166MB from NONTEMPORAL 16B partial-line
// writes): stage 8 bases (16 floats) in VGPRs, then 4 consecutive PLAIN
// dwordx4 stores fully covering the lane's own 64B-aligned chunk. L2
// merges same-lane consecutive sector writes (R4's FETCH=2MB shows no
// read-fill on partial writes), so lines evict fully dirty -> no RMW.
//
// Re[z^d]: R_k = 2x R_{k-1} - (x^2+y^2) R_{k-2},  R_0=1, R_1=x.
// Al = exp2(-0.5*log2e*d(d+1)*(r+eps))  (0.5/(1/(r+e)+e) ~= 0.5(r+e), 1e-8 rel).

#define NBASIS 32
#define PLEN 10
#define EPSV 1e-8f
#define LOG2E 1.44269504088896340736f

typedef float f32x4 __attribute__((ext_vector_type(4)));

__global__ __launch_bounds__(256) void randish_kernel(
    const float* __restrict__ vec,        // (B,3)
    const float* __restrict__ rough,      // (B,)
    const float* __restrict__ mats,       // (32,3,3)
    const float* __restrict__ coeffs,     // (32,10) increasing power
    const float* __restrict__ cscale,     // (32,)
    const float* __restrict__ y0n,        // (32,)
    const int*   __restrict__ degs,       // (32,)
    float* __restrict__ out,              // (B,64)
    int B)
{
    const int b = blockIdx.x * blockDim.x + threadIdx.x;
    if (b >= B) return;

    const float v0 = vec[b * 3 + 0];
    const float v1 = vec[b * 3 + 1];
    const float v2 = vec[b * 3 + 2];
    // Al = exp2( d*(d+1) * tec ),  tec = -0.5*log2e*(r+eps)
    const float tec = (rough[b] + EPSV) * (-0.5f * LOG2E);

    f32x4* dst = reinterpret_cast<f32x4*>(out + (size_t)b * 64);

#pragma unroll
    for (int g = 0; g < 4; ++g) {         // 4 groups x 8 bases
        f32x4 st[4];                      // 16-float staging (one 64B chunk)
#pragma unroll
        for (int j = 0; j < 8; ++j) {
            const int n = g * 8 + j;      // compile-time -> literal offsets
            const int d   = degs[n];      // wave-uniform -> SGPR
            const int par = d & 1;        // uniform

            // rotate (|rv| == 1); mats entries are uniform scalar operands
            const float xh = fmaf(v0, mats[n*9+0], fmaf(v1, mats[n*9+3], v2 * mats[n*9+6]));
            const float yh = fmaf(v0, mats[n*9+1], fmaf(v1, mats[n*9+4], v2 * mats[n*9+7]));
            const float ct = fmaf(v0, mats[n*9+2], fmaf(v1, mats[n*9+5], v2 * mats[n*9+8]));

            // Legendre: P_l(ct) = ct^par * H(ct^2), parity-compressed
            const float ct2 = ct * ct;
            float v = coeffs[n*PLEN + par + 8];
            v = fmaf(v, ct2, coeffs[n*PLEN + par + 6]);
            v = fmaf(v, ct2, coeffs[n*PLEN + par + 4]);
            v = fmaf(v, ct2, coeffs[n*PLEN + par + 2]);
            v = fmaf(v, ct2, coeffs[n*PLEN + par + 0]);
            if (par) v *= ct;             // uniform branch

            // Re[(xh+i*yh)^d]: uniform trip count (deg=1 -> zero iterations)
            float R = xh;
            if (d > 1) {
                const float ss  = fmaf(yh, yh, xh * xh);
                const float m2x = xh + xh;
                float Rm2 = 1.0f, Rm1 = xh;
                for (int k = 2; k <= d; ++k) {
                    const float Rk = fmaf(m2x, Rm1, -(ss * Rm2));
                    Rm2 = Rm1;
                    Rm1 = Rk;
                }
                R = Rm1;
            }
            float cs = cscale[n];
            if (par) cs = -cs;            // fold (-1)^deg, uniform

            const float al = __builtin_amdgcn_exp2f((float)(d * (d + 1)) * tec);

            st[j >> 1][(j & 1) * 2 + 0] = al * (y0n[n] * v);
            st[j >> 1][(j & 1) * 2 + 1] = al * (cs * R);
        }
        // 4 plain dwordx4 stores: this lane's own 64B chunk, fully covered
        dst[g * 4 + 0] = st[0];
        dst[g * 4 + 1] = st[1];
        dst[g * 4 + 2] = st[2];
        dst[g * 4 + 3] = st[3];
    }
}

extern "C" void kernel_launch(void* const* d_in, const int* in_sizes, int n_in,
                              void* d_out, int out_size, void* d_ws, size_t ws_size,
                              hipStream_t stream) {
    const float* vec    = (const float*)d_in[0];
    const float* rough  = (const float*)d_in[1];
    const float* mats   = (const float*)d_in[2];
    const float* coeffs = (const float*)d_in[3];
    const float* cscale = (const float*)d_in[4];
    const float* y0n    = (const float*)d_in[5];
    const int*   degs   = (const int*)d_in[6];
    float* out = (float*)d_out;

    const int B = in_sizes[1];            // roughness element count (262144)
    const int block = 256;
    const int grid = (B + block - 1) / block;

    randish_kernel<<<grid, block, 0, stream>>>(vec, rough, mats, coeffs, cscale,
                                               y0n, degs, out, B);
}

// Round 10
// 23.832 us; speedup vs baseline: 1.2981x; 1.2981x over previous
//
#include <hip/hip_runtime.h>
#include <math.h>

// RandISH, cooperative-tile layout:
//   out[b, 2n+0] = Al(deg_n, r_b) * y0_norm[n] * P_l(ct)
//   out[b, 2n+1] = Al * cscale[n] * (-1)^deg * Re[(rx + i*ry)^deg]
// rv = vec[b] @ M[n]; rotation preserves |vec|=1 -> no normalization.
//
// Block = 1024 threads = 16 waves, owns a 64-direction tile (64x64 floats).
//   lane (0..63)  = direction b       -> coalesced input loads
//   wave (0..15)  = bases n=2w, 2w+1  -> deg/mats/coeffs WAVE-UNIFORM
//     (readfirstlane-forced SGPR: scalar loads, uniform branches, and the
//      Re[z^d] recurrence runs only deg-1 real iterations; ~54% run zero).
// Results staged in LDS [64][65] (odd stride -> <=2-way banks = free), one
// barrier, then each thread stores ONE plain dwordx4, consecutive lanes
// consecutive 16B -> perfect full-line coalescing, 32 waves/CU resident.
//
// This fixes all three prior store failures: R4 (NT 16B partials, 166MB
// WRITE amplification), R6 (9 waves/CU during store), R8 (256B-interleaved
// dwordx4, 4x L2 write transactions).
//
// Re[z^d]: R_k = 2x R_{k-1} - (x^2+y^2) R_{k-2},  R_0=1, R_1=x.
// Al = exp2(-0.5*log2e*d(d+1)*(r+eps))  (0.5/(1/(r+e)+e) ~= 0.5(r+e), 1e-8 rel).

#define NBASIS 32
#define PLEN 10
#define EPSV 1e-8f
#define LOG2E 1.44269504088896340736f
#define ROWD 65   // LDS row stride in dwords (odd -> conflict-free)

typedef float f32x4 __attribute__((ext_vector_type(4)));

__global__ __launch_bounds__(1024) void randish_kernel(
    const float* __restrict__ vec,        // (B,3)
    const float* __restrict__ rough,      // (B,)
    const float* __restrict__ mats,       // (32,3,3)
    const float* __restrict__ coeffs,     // (32,10) increasing power
    const float* __restrict__ cscale,     // (32,)
    const float* __restrict__ y0n,        // (32,)
    const int*   __restrict__ degs,       // (32,)
    float* __restrict__ out,              // (B,64)
    int B)
{
    __shared__ float lds[64 * ROWD];      // 16.64 KB -> 2 blocks/CU, 32 waves/CU

    const int t    = threadIdx.x;         // 0..1023
    const int lane = t & 63;              // direction within tile
    const int w    = t >> 6;              // wave id 0..15
    const int b0   = blockIdx.x * 64;
    const int b    = b0 + lane;           // B % 64 == 0 -> always in range

    const float v0 = vec[b * 3 + 0];
    const float v1 = vec[b * 3 + 1];
    const float v2 = vec[b * 3 + 2];
    // Al = exp2( d*(d+1) * tec ),  tec = -0.5*log2e*(r+eps)
    const float tec = (rough[b] + EPSV) * (-0.5f * LOG2E);

    float* row = &lds[lane * ROWD];

#pragma unroll
    for (int s = 0; s < 2; ++s) {
        // n and everything derived from it are wave-uniform -> SGPRs
        const int n = __builtin_amdgcn_readfirstlane(2 * w + s);
        const int d = __builtin_amdgcn_readfirstlane(degs[n]);
        const int par = d & 1;

        // rotate (|rv| == 1); mats entries are uniform scalar operands
        const float xh = fmaf(v0, mats[n*9+0], fmaf(v1, mats[n*9+3], v2 * mats[n*9+6]));
        const float yh = fmaf(v0, mats[n*9+1], fmaf(v1, mats[n*9+4], v2 * mats[n*9+7]));
        const float ct = fmaf(v0, mats[n*9+2], fmaf(v1, mats[n*9+5], v2 * mats[n*9+8]));

        // Legendre: P_l(ct) = ct^par * H(ct^2), parity-compressed, zero-padded
        const float ct2 = ct * ct;
        float v = coeffs[n*PLEN + par + 8];
        v = fmaf(v, ct2, coeffs[n*PLEN + par + 6]);
        v = fmaf(v, ct2, coeffs[n*PLEN + par + 4]);
        v = fmaf(v, ct2, coeffs[n*PLEN + par + 2]);
        v = fmaf(v, ct2, coeffs[n*PLEN + par + 0]);
        if (par) v *= ct;                 // uniform branch

        // Re[(xh+i*yh)^d]: uniform trip count (d==1 -> zero iterations)
        float R = xh;
        if (d > 1) {
            const float ss  = fmaf(yh, yh, xh * xh);
            const float m2x = xh + xh;
            float Rm2 = 1.0f, Rm1 = xh;
            for (int k = 2; k <= d; ++k) {
                const float Rk = fmaf(m2x, Rm1, -(ss * Rm2));
                Rm2 = Rm1;
                Rm1 = Rk;
            }
            R = Rm1;
        }
        float cs = cscale[n];
        if (par) cs = -cs;                // fold (-1)^deg, uniform

        const float al = __builtin_amdgcn_exp2f((float)(d * (d + 1)) * tec);

        // LDS write: bank = (65*lane + 2n) % 32 -> <=2-way across 64 lanes
        row[2 * n + 0] = al * (y0n[n] * v);
        row[2 * n + 1] = al * (cs * R);
    }

    __syncthreads();

    // store: tile = 64 b x 64 floats = 16 KB = 1024 dwordx4 chunks, one per
    // thread; consecutive threads -> consecutive 16B -> full-line coalesced
    const int r   = t >> 4;               // source LDS row
    const int c4  = (t & 15) * 4;         // dword column
    const float* src = &lds[r * ROWD + c4];
    f32x4 o = { src[0], src[1], src[2], src[3] };
    reinterpret_cast<f32x4*>(out + (size_t)b0 * 64)[t] = o;
}

extern "C" void kernel_launch(void* const* d_in, const int* in_sizes, int n_in,
                              void* d_out, int out_size, void* d_ws, size_t ws_size,
                              hipStream_t stream) {
    const float* vec    = (const float*)d_in[0];
    const float* rough  = (const float*)d_in[1];
    const float* mats   = (const float*)d_in[2];
    const float* coeffs = (const float*)d_in[3];
    const float* cscale = (const float*)d_in[4];
    const float* y0n    = (const float*)d_in[5];
    const int*   degs   = (const int*)d_in[6];
    float* out = (float*)d_out;

    const int B = in_sizes[1];            // roughness element count (262144)
    const int block = 1024;               // 16 waves; one 64-direction tile
    const int grid = B / 64;              // 4096 tiles

    randish_kernel<<<grid, block, 0, stream>>>(vec, rough, mats, coeffs, cscale,
                                               y0n, degs, out, B);
}

// Round 11
// 22.030 us; speedup vs baseline: 1.4043x; 1.0818x over previous
//
#include <hip/hip_runtime.h>
#include <math.h>

// RandISH, cooperative-tile layout v2 (full residency + 2-tile pipeline):
//   out[b, 2n+0] = Al(deg_n, r_b) * y0_norm[n] * P_l(ct)
//   out[b, 2n+1] = Al * cscale[n] * (-1)^deg * Re[(rx + i*ry)^deg]
// rv = vec[b] @ M[n]; rotation preserves |vec|=1 -> no normalization.
//
// Block = 256 threads = 4 waves, owns TWO 64-direction tiles (processed
// back-to-back; both tiles' inputs prefetched at kernel entry).
//   lane (0..63) = direction b          -> coalesced input loads
//   wave w (0..3) = bases n=8w..8w+7    -> deg/mats/coeffs WAVE-UNIFORM
//     (readfirstlane-forced SGPR: scalar loads, uniform branches; Re[z^d]
//      recurrence runs only deg-1 real iterations, ~54% run zero).
// Results staged in LDS [64][65] (odd stride -> <=2-way banks = free); one
// barrier; 4 plain dwordx4 stores/thread, consecutive threads consecutive
// 16B -> perfect full-line coalescing.
// grid = 2048 blocks of 256 -> 8 blocks/CU: EVERYTHING resident in one
// generation (no launch serialization), 32 waves/CU during the store
// stream; 8 independent blocks/CU interleave their compute/barrier/store
// phases so the write pipe never drains (R9's gap: 2 blocks/CU, 8 serial
// generations of {load-latency + compute + barrier} heads).
//
// Re[z^d]: R_k = 2x R_{k-1} - (x^2+y^2) R_{k-2},  R_0=1, R_1=x.
// Al = exp2(-0.5*log2e*d(d+1)*(r+eps))  (0.5/(1/(r+e)+e) ~= 0.5(r+e), 1e-8 rel).

#define NBASIS 32
#define PLEN 10
#define EPSV 1e-8f
#define LOG2E 1.44269504088896340736f
#define ROWD 65   // LDS row stride in dwords (odd -> conflict-free)
#define NT 2      // tiles per block

typedef float f32x4 __attribute__((ext_vector_type(4)));

__global__ __launch_bounds__(256) void randish_kernel(
    const float* __restrict__ vec,        // (B,3)
    const float* __restrict__ rough,      // (B,)
    const float* __restrict__ mats,       // (32,3,3)
    const float* __restrict__ coeffs,     // (32,10) increasing power
    const float* __restrict__ cscale,     // (32,)
    const float* __restrict__ y0n,        // (32,)
    const int*   __restrict__ degs,       // (32,)
    float* __restrict__ out,              // (B,64)
    int B)
{
    __shared__ float lds[64 * ROWD];      // 16.6 KB

    const int t    = threadIdx.x;         // 0..255
    const int lane = t & 63;              // direction within tile
    const int w    = t >> 6;              // wave id 0..3

    // ---- prefetch BOTH tiles' inputs (independent loads, one window) ----
    float V0[NT], V1[NT], V2[NT], TC[NT];
    int   BB[NT];
#pragma unroll
    for (int it = 0; it < NT; ++it) {
        const int b0 = (blockIdx.x * NT + it) * 64;
        const int b  = b0 + lane;         // B % (64*NT) == 0 -> in range
        BB[it] = b0;
        V0[it] = vec[b * 3 + 0];
        V1[it] = vec[b * 3 + 1];
        V2[it] = vec[b * 3 + 2];
        // Al = exp2( d*(d+1) * tc ),  tc = -0.5*log2e*(r+eps)
        TC[it] = (rough[b] + EPSV) * (-0.5f * LOG2E);
    }

    float* row = &lds[lane * ROWD];

#pragma unroll
    for (int it = 0; it < NT; ++it) {
        const float v0 = V0[it], v1 = V1[it], v2 = V2[it], tc = TC[it];

#pragma unroll
        for (int j = 0; j < 8; ++j) {
            // n and all derived per-n data are wave-uniform -> SGPRs
            const int n = __builtin_amdgcn_readfirstlane(8 * w + j);
            const int d = __builtin_amdgcn_readfirstlane(degs[n]);
            const int par = d & 1;

            // rotate (|rv| == 1); mats entries are uniform scalar operands
            const float xh = fmaf(v0, mats[n*9+0], fmaf(v1, mats[n*9+3], v2 * mats[n*9+6]));
            const float yh = fmaf(v0, mats[n*9+1], fmaf(v1, mats[n*9+4], v2 * mats[n*9+7]));
            const float ct = fmaf(v0, mats[n*9+2], fmaf(v1, mats[n*9+5], v2 * mats[n*9+8]));

            // Legendre: P_l(ct) = ct^par * H(ct^2), parity-compressed
            const float ct2 = ct * ct;
            float v = coeffs[n*PLEN + par + 8];
            v = fmaf(v, ct2, coeffs[n*PLEN + par + 6]);
            v = fmaf(v, ct2, coeffs[n*PLEN + par + 4]);
            v = fmaf(v, ct2, coeffs[n*PLEN + par + 2]);
            v = fmaf(v, ct2, coeffs[n*PLEN + par + 0]);
            if (par) v *= ct;             // uniform branch

            // Re[(xh+i*yh)^d]: uniform trip count (d==1 -> zero iterations)
            float R = xh;
            if (d > 1) {
                const float ss  = fmaf(yh, yh, xh * xh);
                const float m2x = xh + xh;
                float Rm2 = 1.0f, Rm1 = xh;
                for (int k = 2; k <= d; ++k) {
                    const float Rk = fmaf(m2x, Rm1, -(ss * Rm2));
                    Rm2 = Rm1;
                    Rm1 = Rk;
                }
                R = Rm1;
            }
            float cs = cscale[n];
            if (par) cs = -cs;            // fold (-1)^deg, uniform

            const float al = __builtin_amdgcn_exp2f((float)(d * (d + 1)) * tc);

            // LDS write: bank = (lane + 2n) % 32 -> 2-way across 64 lanes (free)
            row[2 * n + 0] = al * (y0n[n] * v);
            row[2 * n + 1] = al * (cs * R);
        }

        __syncthreads();

        // store tile: 64 b x 64 floats = 16 KB = 1024 dwordx4 chunks;
        // 4 per thread, consecutive threads -> consecutive 16B (full lines)
        f32x4* outp = reinterpret_cast<f32x4*>(out + (size_t)BB[it] * 64);
#pragma unroll
        for (int p = 0; p < 4; ++p) {
            const int c  = p * 256 + t;   // chunk index in tile
            const int r  = c >> 4;        // source LDS row
            const int c4 = (c & 15) * 4;  // dword column
            const float* src = &lds[r * ROWD + c4];
            f32x4 o = { src[0], src[1], src[2], src[3] };
            outp[c] = o;
        }

        if (it + 1 < NT) __syncthreads(); // LDS reuse guard
    }
}

extern "C" void kernel_launch(void* const* d_in, const int* in_sizes, int n_in,
                              void* d_out, int out_size, void* d_ws, size_t ws_size,
                              hipStream_t stream) {
    const float* vec    = (const float*)d_in[0];
    const float* rough  = (const float*)d_in[1];
    const float* mats   = (const float*)d_in[2];
    const float* coeffs = (const float*)d_in[3];
    const float* cscale = (const float*)d_in[4];
    const float* y0n    = (const float*)d_in[5];
    const int*   degs   = (const int*)d_in[6];
    float* out = (float*)d_out;

    const int B = in_sizes[1];            // roughness element count (262144)
    const int block = 256;                // 4 waves; 2 tiles of 64 directions
    const int grid = B / (64 * NT);       // 2048 blocks -> all resident

    randish_kernel<<<grid, block, 0, stream>>>(vec, rough, mats, coeffs, cscale,
                                               y0n, degs, out, B);
}

// Round 12
// 20.494 us; speedup vs baseline: 1.5095x; 1.0749x over previous
//
#include <hip/hip_runtime.h>
#include <math.h>

// RandISH, cooperative-tile layout v3 (v2 + nontemporal full-line stores):
//   out[b, 2n+0] = Al(deg_n, r_b) * y0_norm[n] * P_l(ct)
//   out[b, 2n+1] = Al * cscale[n] * (-1)^deg * Re[(rx + i*ry)^deg]
// rv = vec[b] @ M[n]; rotation preserves |vec|=1 -> no normalization.
//
// Block = 256 threads = 4 waves, owns TWO 64-direction tiles.
//   lane (0..63) = direction b          -> coalesced input loads
//   wave w (0..3) = bases n=8w..8w+7    -> deg/mats/coeffs WAVE-UNIFORM
//     (readfirstlane-forced SGPR: scalar loads, uniform branches; Re[z^d]
//      recurrence runs only deg-1 real iterations, ~54% run zero).
// Results staged in LDS [64][65] (odd stride -> <=2-way banks = free); one
// barrier; 4 dwordx4 NONTEMPORAL stores/thread: consecutive threads write
// consecutive 16B -> full 128B lines -> NT streams at HBM rate without L2
// allocate/evict double-handling (R4's NT failure was 16B PARTIAL lines at
// stride 256B; full-line NT is the fillBuffer path, 6.5 TB/s measured).
// grid = 2048 blocks -> 8 blocks/CU, all resident, phases interleave.
//
// Re[z^d]: R_k = 2x R_{k-1} - (x^2+y^2) R_{k-2},  R_0=1, R_1=x.
// Al = exp2(-0.5*log2e*d(d+1)*(r+eps))  (0.5/(1/(r+e)+e) ~= 0.5(r+e), 1e-8 rel).

#define NBASIS 32
#define PLEN 10
#define EPSV 1e-8f
#define LOG2E 1.44269504088896340736f
#define ROWD 65   // LDS row stride in dwords (odd -> conflict-free)
#define NT 2      // tiles per block

typedef float f32x4 __attribute__((ext_vector_type(4)));

__global__ __launch_bounds__(256) void randish_kernel(
    const float* __restrict__ vec,        // (B,3)
    const float* __restrict__ rough,      // (B,)
    const float* __restrict__ mats,       // (32,3,3)
    const float* __restrict__ coeffs,     // (32,10) increasing power
    const float* __restrict__ cscale,     // (32,)
    const float* __restrict__ y0n,        // (32,)
    const int*   __restrict__ degs,       // (32,)
    float* __restrict__ out,              // (B,64)
    int B)
{
    __shared__ float lds[64 * ROWD];      // 16.6 KB

    const int t    = threadIdx.x;         // 0..255
    const int lane = t & 63;              // direction within tile
    const int w    = t >> 6;              // wave id 0..3

    // ---- prefetch BOTH tiles' inputs (independent loads, one window) ----
    float V0[NT], V1[NT], V2[NT], TC[NT];
    int   BB[NT];
#pragma unroll
    for (int it = 0; it < NT; ++it) {
        const int b0 = (blockIdx.x * NT + it) * 64;
        const int b  = b0 + lane;         // B % (64*NT) == 0 -> in range
        BB[it] = b0;
        V0[it] = vec[b * 3 + 0];
        V1[it] = vec[b * 3 + 1];
        V2[it] = vec[b * 3 + 2];
        // Al = exp2( d*(d+1) * tc ),  tc = -0.5*log2e*(r+eps)
        TC[it] = (rough[b] + EPSV) * (-0.5f * LOG2E);
    }

    float* row = &lds[lane * ROWD];

#pragma unroll
    for (int it = 0; it < NT; ++it) {
        const float v0 = V0[it], v1 = V1[it], v2 = V2[it], tc = TC[it];

#pragma unroll
        for (int j = 0; j < 8; ++j) {
            // n and all derived per-n data are wave-uniform -> SGPRs
            const int n = __builtin_amdgcn_readfirstlane(8 * w + j);
            const int d = __builtin_amdgcn_readfirstlane(degs[n]);
            const int par = d & 1;

            // rotate (|rv| == 1); mats entries are uniform scalar operands
            const float xh = fmaf(v0, mats[n*9+0], fmaf(v1, mats[n*9+3], v2 * mats[n*9+6]));
            const float yh = fmaf(v0, mats[n*9+1], fmaf(v1, mats[n*9+4], v2 * mats[n*9+7]));
            const float ct = fmaf(v0, mats[n*9+2], fmaf(v1, mats[n*9+5], v2 * mats[n*9+8]));

            // Legendre: P_l(ct) = ct^par * H(ct^2), parity-compressed
            const float ct2 = ct * ct;
            float v = coeffs[n*PLEN + par + 8];
            v = fmaf(v, ct2, coeffs[n*PLEN + par + 6]);
            v = fmaf(v, ct2, coeffs[n*PLEN + par + 4]);
            v = fmaf(v, ct2, coeffs[n*PLEN + par + 2]);
            v = fmaf(v, ct2, coeffs[n*PLEN + par + 0]);
            if (par) v *= ct;             // uniform branch

            // Re[(xh+i*yh)^d]: uniform trip count (d==1 -> zero iterations)
            float R = xh;
            if (d > 1) {
                const float ss  = fmaf(yh, yh, xh * xh);
                const float m2x = xh + xh;
                float Rm2 = 1.0f, Rm1 = xh;
                for (int k = 2; k <= d; ++k) {
                    const float Rk = fmaf(m2x, Rm1, -(ss * Rm2));
                    Rm2 = Rm1;
                    Rm1 = Rk;
                }
                R = Rm1;
            }
            float cs = cscale[n];
            if (par) cs = -cs;            // fold (-1)^deg, uniform

            const float al = __builtin_amdgcn_exp2f((float)(d * (d + 1)) * tc);

            // LDS write: bank = (lane + 2n) % 32 -> 2-way across 64 lanes (free)
            row[2 * n + 0] = al * (y0n[n] * v);
            row[2 * n + 1] = al * (cs * R);
        }

        __syncthreads();

        // store tile: 64 b x 64 floats = 16 KB = 1024 dwordx4 chunks;
        // 4 per thread, consecutive threads -> consecutive 16B -> full
        // 128B lines -> NT streaming (no L2 allocate/evict double-handling)
        f32x4* outp = reinterpret_cast<f32x4*>(out + (size_t)BB[it] * 64);
#pragma unroll
        for (int p = 0; p < 4; ++p) {
            const int c  = p * 256 + t;   // chunk index in tile
            const int r  = c >> 4;        // source LDS row
            const int c4 = (c & 15) * 4;  // dword column
            const float* src = &lds[r * ROWD + c4];
            f32x4 o = { src[0], src[1], src[2], src[3] };
            __builtin_nontemporal_store(o, outp + c);
        }

        if (it + 1 < NT) __syncthreads(); // LDS reuse guard
    }
}

extern "C" void kernel_launch(void* const* d_in, const int* in_sizes, int n_in,
                              void* d_out, int out_size, void* d_ws, size_t ws_size,
                              hipStream_t stream) {
    const float* vec    = (const float*)d_in[0];
    const float* rough  = (const float*)d_in[1];
    const float* mats   = (const float*)d_in[2];
    const float* coeffs = (const float*)d_in[3];
    const float* cscale = (const float*)d_in[4];
    const float* y0n    = (const float*)d_in[5];
    const int*   degs   = (const int*)d_in[6];
    float* out = (float*)d_out;

    const int B = in_sizes[1];            // roughness element count (262144)
    const int block = 256;                // 4 waves; 2 tiles of 64 directions
    const int grid = B / (64 * NT);       // 2048 blocks -> all resident

    randish_kernel<<<grid, block, 0, stream>>>(vec, rough, mats, coeffs, cscale,
                                               y0n, degs, out, B);
}